// Round 11
// baseline (1065.624 us; speedup 1.0000x reference)
//
#include <hip/hip_runtime.h>
#include <cstdint>

// LSTM: B=1024, T=336, I=64, H=256, gates 4H=1024, K = I+H = 320.
// R14 = R13 with BATCHED retry in phase-2. R13's counters exposed the flaw:
// per-tile serial retry = 6 serial L3 round trips per step (tile f's retry
// runs while tiles f+1..5 sit on stale snapshots -> each discovers staleness
// only after the previous one clears). Fix: check all 6 tile-tags, reissue
// ALL stale tiles together, ONE vmcnt(0), recheck -> pay max(RT), not sum.
// Everything else unchanged from R13 (verified correct, absmax 0.0039):
// 64 groups x 4 members, 16 batches/group, 64 gate-cols/member, 1 barrier/
// step, remote h polled per-lane directly into MFMA B-fragments, t=1 via
// memset tag 0, bounded valve, device-scope sc0+sc1 exchange.

#define NGROUP  64
#define BATCH_G 16
#define T_STEPS 336
#define I_DIM   64
#define H_DIM   256
#define VSTRIDE 136   // ushorts per staged row: x(64) + own-h(64) + 8 pad
#define PAIRS   128   // h-pairs per batch row (256 cols / 2)
#define OUT_HALF 262144  // 1024*256
#define VALVE   (1 << 12)   // bounded poll: bench always returns a verdict

typedef __attribute__((ext_vector_type(8))) __bf16 bf16x8;
typedef __attribute__((ext_vector_type(8))) unsigned short ushort8_t;
typedef __attribute__((ext_vector_type(4))) float f32x4;
typedef __attribute__((ext_vector_type(4))) unsigned uint32x4;
typedef __attribute__((ext_vector_type(2))) unsigned uint32x2;

__device__ inline unsigned short f2bf(float f) {
  unsigned u = __builtin_bit_cast(unsigned, f);
  return (unsigned short)((u + 0x7fffu + ((u >> 16) & 1u)) >> 16);
}
__device__ inline float sigf(float x) { return 1.f / (1.f + __expf(-x)); }
__device__ inline float tanhfast(float x) { return 1.f - 2.f / (1.f + __expf(2.f * x)); }

// slot s (0..9) -> k-tile index kt (0..9). Slots 0,1 = x tiles; 2,3 = own h
// tiles (kt = 2+2*mid, 3+2*mid); 4..9 = the 6 remote h tiles in kt order.
__device__ inline int slot_kt(int s, int mid) {
  return (s < 2) ? s
       : (s < 4) ? (2 + 2 * mid + (s - 2))
       : (((s - 4) < 2 * mid) ? (s - 2) : s);
}

__device__ inline void st_pair(uint32x2* p, uint32x2 v) {
  asm volatile("global_store_dwordx2 %0, %1, off sc0 sc1" :: "v"(p), "v"(v) : "memory");
}

// issue 4 tagged-pair loads for one tile (no wait)
__device__ inline void issue4(const uint32x2* pf, uint32x2& r0, uint32x2& r1,
                              uint32x2& r2, uint32x2& r3) {
  asm volatile(
      "global_load_dwordx2 %0, %4, off sc0 sc1\n\t"
      "global_load_dwordx2 %1, %4, off offset:128 sc0 sc1\n\t"
      "global_load_dwordx2 %2, %4, off offset:256 sc0 sc1\n\t"
      "global_load_dwordx2 %3, %4, off offset:384 sc0 sc1"
      : "=&v"(r0), "=&v"(r1), "=&v"(r2), "=&v"(r3)
      : "v"(pf) : "memory");
}

__global__ __launch_bounds__(512, 2) void lstm_persistent(
    const float* __restrict__ x, const float* __restrict__ W_ih,
    const float* __restrict__ W_hh, const float* __restrict__ b_ih,
    const float* __restrict__ b_hh, float* __restrict__ out,
    uint32x2* __restrict__ hbuf)
{
  __shared__ __align__(16) unsigned short v_lds[2][BATCH_G * VSTRIDE];

  const int tid  = threadIdx.x;
  const int gid  = blockIdx.x & 63;   // batch group (16 batches)
  const int mid  = blockIdx.x >> 6;   // member 0..3 (owns gate cols [mid*64, +64))
  const int wv   = tid >> 6;          // wave 0..7
  const int l    = tid & 63;
  const int l15  = l & 15, quad = l >> 4;
  const int rg   = wv;                // row-group 0..7: local cols [8*rg, +8)

  // ---- A-fragments in SLOT order (0,1=x; 2,3=own h; 4..9=remote h) ----
  bf16x8 afrag[2][10];
#pragma unroll
  for (int rt = 0; rt < 2; ++rt) {
    int grow = (l15 & 3) * H_DIM + mid * 64 + rg * 8 + rt * 4 + (l15 >> 2);
    const float* wih_row = W_ih + (long)grow * I_DIM;
    const float* whh_row = W_hh + (long)grow * H_DIM;
#pragma unroll
    for (int s = 0; s < 10; ++s) {
      int kt = slot_kt(s, mid);
      int kbase = kt * 32 + quad * 8;
      ushort8_t a;
#pragma unroll
      for (int e = 0; e < 8; ++e) {
        int k = kbase + e;
        float v = (k < I_DIM) ? wih_row[k] : whh_row[k - I_DIM];
        a[e] = f2bf(v);
      }
      afrag[rt][s] = __builtin_bit_cast(bf16x8, a);
    }
  }

  // ---- bias as acc-init: lane's cell = (col = rg*8+rt*4+quad, batch = l15) ----
  f32x4 bias[2];
#pragma unroll
  for (int rt = 0; rt < 2; ++rt) {
#pragma unroll
    for (int g = 0; g < 4; ++g) {
      int grow = g * H_DIM + mid * 64 + rg * 8 + rt * 4 + quad;
      bias[rt][g] = b_ih[grow] + b_hh[grow];
    }
  }

  const int batch = l15;              // 0..15 within group
  float c_reg[2] = {0.f, 0.f};
  float h_keep[2];

  // ---- x staging: 32 threads per batch row (float2 each) ----
  const int b_stage = tid >> 5;          // 0..15
  const int x_i2    = (tid & 31) * 2;    // 2 floats of x
  const float* xrow = x + ((long)(gid * BATCH_G + b_stage)) * T_STEPS * I_DIM + x_i2;

  // ---- consumer: per-lane remote fragment source. For remote tile kt, lane
  //      needs h-cols [(kt-2)*32 + quad*8, +8) of its batch = pairs
  //      p0..p0+3 (p0 = (kt-2)*16 + quad*4), each 8 B at stride 128 B. ----
  const uint32x2* rbase0 = hbuf + (long)gid * PAIRS * BATCH_G + batch;

  // ---- producer store: pair = mid*32 + rg*4 + rt*2 + (quad>>1), batch = l15
  //      -> lanes l15 contiguous => 128 B runs, full sectors. ----
  uint32x2* st_base = hbuf + ((long)gid * PAIRS + mid * 32 + rg * 4 + (quad >> 1)) * BATCH_G + batch;
  const long buf_stride = (long)NGROUP * PAIRS * BATCH_G;

  // ---- pre-zero own-h region of buffer 1 (t=1 phase-1 reads zeros) ----
  {
    int zr = tid >> 5, zc = (tid & 31) * 2;
    *(unsigned*)&v_lds[1][zr * VSTRIDE + I_DIM + zc] = 0u;
  }

  // ---- x prefetch one step ahead (HBM latency off the critical path) ----
  float2 xv = *(const float2*)xrow;     // row for t=1

  for (int t = 1; t <= T_STEPS; ++t) {
    unsigned short* vbuf = v_lds[t & 1];

    // ---- stage prefetched x_t, then issue the next row's load ----
    {
      ushort2 xb;
      xb.x = f2bf(xv.x); xb.y = f2bf(xv.y);
      *(ushort2*)&vbuf[b_stage * VSTRIDE + x_i2] = xb;
    }
    if (t < T_STEPS) xv = *(const float2*)(xrow + (long)t * I_DIM);

    __syncthreads();   // the ONLY barrier per step

    // ---- phase-1a: x tiles (slots 0,1). LDS row = [x(64) | own-h(64)] ----
    f32x4 acc0 = bias[0], acc1 = bias[1];
    const unsigned short* vb = vbuf + (unsigned)batch * VSTRIDE + quad * 8;
#pragma unroll
    for (int s = 0; s < 2; ++s) {
      bf16x8 bv = __builtin_bit_cast(bf16x8, *(const uint32x4*)(vb + s * 32));
      acc0 = __builtin_amdgcn_mfma_f32_16x16x32_bf16(afrag[0][s], bv, acc0, 0, 0, 0);
      acc1 = __builtin_amdgcn_mfma_f32_16x16x32_bf16(afrag[1][s], bv, acc1, 0, 0, 0);
    }

    // ---- bulk-issue 24 remote pair loads (6 tiles x 4 pairs, no wait) ----
    uint32x2 rr[6][4];
    const uint32x2* rb = rbase0 + ((t - 1) & 1) * buf_stride;
#pragma unroll
    for (int f = 0; f < 6; ++f) {
      int kt = slot_kt(4 + f, mid);
      issue4(rb + ((kt - 2) * 16 + quad * 4) * BATCH_G,
             rr[f][0], rr[f][1], rr[f][2], rr[f][3]);
    }

    // ---- phase-1b: own-h tiles (slots 2,3) — covers the load round trip ----
#pragma unroll
    for (int s = 2; s < 4; ++s) {
      bf16x8 bv = __builtin_bit_cast(bf16x8, *(const uint32x4*)(vb + s * 32));
      acc0 = __builtin_amdgcn_mfma_f32_16x16x32_bf16(afrag[0][s], bv, acc0, 0, 0, 0);
      acc1 = __builtin_amdgcn_mfma_f32_16x16x32_bf16(afrag[1][s], bv, acc1, 0, 0, 0);
    }

    // ---- phase-2: BATCHED poll. Check all 6 tiles; reissue ALL stale tiles
    //      together; one vmcnt(0); recheck. Pays max(RT), not sum(RT). ----
    const unsigned tag = (unsigned)(t - 1);   // t==1: memset tags==0 match, data==0
    {
      // one wait for the whole bulk issue; tie all rr regs to it
#pragma unroll
      for (int f = 0; f < 6; ++f)
        asm volatile("s_waitcnt vmcnt(0)"
                     : "+v"(rr[f][0]), "+v"(rr[f][1]), "+v"(rr[f][2]), "+v"(rr[f][3])
                     :: "memory");
      bool ok[6];
#pragma unroll
      for (int f = 0; f < 6; ++f)
        ok[f] = (rr[f][0][0] == tag) & (rr[f][1][0] == tag) &
                (rr[f][2][0] == tag) & (rr[f][3][0] == tag);
      int it = 0;
      while (!(ok[0] & ok[1] & ok[2] & ok[3] & ok[4] & ok[5])) {
        if (++it > VALVE) break;   // bounded: bench always returns a verdict
        __builtin_amdgcn_s_sleep(1);
#pragma unroll
        for (int f = 0; f < 6; ++f) {
          if (!ok[f]) {
            int kt = slot_kt(4 + f, mid);
            issue4(rb + ((kt - 2) * 16 + quad * 4) * BATCH_G,
                   rr[f][0], rr[f][1], rr[f][2], rr[f][3]);
          }
        }
#pragma unroll
        for (int f = 0; f < 6; ++f)
          asm volatile("s_waitcnt vmcnt(0)"
                       : "+v"(rr[f][0]), "+v"(rr[f][1]), "+v"(rr[f][2]), "+v"(rr[f][3])
                       :: "memory");
#pragma unroll
        for (int f = 0; f < 6; ++f)
          if (!ok[f])
            ok[f] = (rr[f][0][0] == tag) & (rr[f][1][0] == tag) &
                    (rr[f][2][0] == tag) & (rr[f][3][0] == tag);
      }
    }

    // ---- phase-2 MFMA: all 6 remote tiles from registers ----
#pragma unroll
    for (int f = 0; f < 6; ++f) {
      uint32x4 dw;
      dw[0] = rr[f][0][1]; dw[1] = rr[f][1][1];
      dw[2] = rr[f][2][1]; dw[3] = rr[f][3][1];
      bf16x8 bv = __builtin_bit_cast(bf16x8, dw);
      acc0 = __builtin_amdgcn_mfma_f32_16x16x32_bf16(afrag[0][4 + f], bv, acc0, 0, 0, 0);
      acc1 = __builtin_amdgcn_mfma_f32_16x16x32_bf16(afrag[1][4 + f], bv, acc1, 0, 0, 0);
    }

    // ---- cell fully in registers; own-slice to LDS; tagged pair to global.
    //      Producer-critical path: boost wave priority. ----
    __builtin_amdgcn_s_setprio(1);
    unsigned short* next_own = v_lds[(t + 1) & 1] + (unsigned)batch * VSTRIDE + I_DIM;
#pragma unroll
    for (int rt = 0; rt < 2; ++rt) {
      const f32x4 acc = rt ? acc1 : acc0;
      float c = sigf(acc[1]) * c_reg[rt] + sigf(acc[0]) * tanhfast(acc[2]);
      float h = sigf(acc[3]) * tanhfast(c);
      c_reg[rt] = c; h_keep[rt] = h;
      unsigned short hb16 = f2bf(h);
      next_own[rg * 8 + rt * 4 + quad] = hb16;                    // LDS shortcut (own WG)
      unsigned hb = (unsigned)hb16;
      unsigned partner = (unsigned)__shfl_xor((int)hb, 16, 64);   // col^1, same batch
      if (!(quad & 1)) {
        uint32x2 pv;
        pv[0] = (unsigned)t;                  // tag
        pv[1] = hb | (partner << 16);         // (col, col+1)
        st_pair(st_base + rt * 2 * BATCH_G + (t & 1) * buf_stride, pv);  // fire-and-forget
      }
    }
    __builtin_amdgcn_s_setprio(0);
  }

  // ---- outputs: h_T then c_T, fp32 (pre-bf16-rounding values) ----
#pragma unroll
  for (int rt = 0; rt < 2; ++rt) {
    int gcol = mid * 64 + rg * 8 + rt * 4 + quad;
    long o = (long)(gid * BATCH_G + batch) * H_DIM + gcol;
    out[o]            = h_keep[rt];
    out[OUT_HALF + o] = c_reg[rt];
  }
}

extern "C" void kernel_launch(void* const* d_in, const int* in_sizes, int n_in,
                              void* d_out, int out_size, void* d_ws, size_t ws_size,
                              hipStream_t stream) {
  const float* x    = (const float*)d_in[0];
  const float* W_ih = (const float*)d_in[1];
  const float* W_hh = (const float*)d_in[2];
  const float* b_ih = (const float*)d_in[3];
  const float* b_hh = (const float*)d_in[4];
  float* out = (float*)d_out;

  uint32x2* hbuf = (uint32x2*)d_ws;   // 2 buffers x 64 groups x 128 pairs x 16 batch x 8 B = 2 MB

  // Clear tags+data: tag 0 == (t=1)-1 makes step 1 read zeros with no special case.
  hipMemsetAsync(d_ws, 0, 2u * NGROUP * PAIRS * BATCH_G * 8u, stream);
  lstm_persistent<<<dim3(256), dim3(512), 0, stream>>>(x, W_ih, W_hh, b_ih, b_hh, out, hbuf);
}

// Round 13
// 930.338 us; speedup vs baseline: 1.1454x; 1.1454x over previous
//
#include <hip/hip_runtime.h>
#include <cstdint>

// LSTM: B=1024, T=336, I=64, H=256, gates 4H=1024, K = I+H = 320.
// R15 (resubmit; prior two container failures diagnosed as infra push/
// acquire timeouts, not kernel): REDUNDANT-COMPUTE fan-in-2 on the R9 base
// (64 groups x 4 members x 512 thr, 16 batches/group). Member m computes
// gate-cols [m*64, m*64+128) mod 256 (its own 64 + next member's 64,
// identical arithmetic -> identical values): 2x MFMA/wave (pipe only 12.6%
// busy) buys: local phase 6/10 tiles (24 MFMA of poll-RT cover, was 8),
// remote tiles 6->4 from 2 partners (was 3) -> poll traffic 12->8 KB/WG/
// step and tail-of-2 at barrier2. R13/R14 lesson kept: LDS staging for
// remote h (per-lane direct-to-reg is an L3-BW trap); R9's proven poll
// timing (issue after x-tiles, check after own-h tiles; R10/R11 proved
// earlier snapshots lose the race). Canonical-only stores (rg<4) keep
// exchange volume unchanged. Bounded valve. Device-scope sc0+sc1.
// NOTE (R12-round audit): the all-LDS single-WG-per-group alternative is
// impossible -- full-K weight residency is an invariant 160 VGPR/wave at
// 16 waves/CU (limit 128); the 4-member split is forced by the RF.

#define NGROUP  64
#define BATCH_G 16
#define T_STEPS 336
#define I_DIM   64
#define H_DIM   256
#define VSTRIDE 336   // ushorts per staged row: x(64) + h(256) + 16 pad
#define PAIRS   128   // h-pairs per batch row (256 cols / 2)
#define OUT_HALF 262144  // 1024*256
#define VALVE   (1 << 12)   // bounded poll: bench always returns a verdict

typedef __attribute__((ext_vector_type(8))) __bf16 bf16x8;
typedef __attribute__((ext_vector_type(8))) unsigned short ushort8_t;
typedef __attribute__((ext_vector_type(4))) float f32x4;
typedef __attribute__((ext_vector_type(4))) unsigned uint32x4;
typedef __attribute__((ext_vector_type(2))) unsigned uint32x2;

__device__ inline unsigned short f2bf(float f) {
  unsigned u = __builtin_bit_cast(unsigned, f);
  return (unsigned short)((u + 0x7fffu + ((u >> 16) & 1u)) >> 16);
}
__device__ inline float sigf(float x) { return 1.f / (1.f + __expf(-x)); }
__device__ inline float tanhfast(float x) { return 1.f - 2.f / (1.f + __expf(2.f * x)); }

// slot s (0..9) -> k-tile kt (0..9). 0,1 = x. 2..5 = the 4 LOCAL h-tiles
// (cols [mid*64, +128) mod 256). 6..9 = the 4 REMOTE h-tiles.
__device__ inline int slot_kt(int s, int mid) {
  return (s < 2) ? s
       : (s < 6) ? (2 + ((2 * mid + (s - 2)) & 7))
       : (2 + ((2 * mid + 4 + (s - 6)) & 7));
}

__device__ inline void st_pair(uint32x2* p, uint32x2 v) {
  asm volatile("global_store_dwordx2 %0, %1, off sc0 sc1" :: "v"(p), "v"(v) : "memory");
}

__global__ __launch_bounds__(512, 1) void lstm_persistent(
    const float* __restrict__ x, const float* __restrict__ W_ih,
    const float* __restrict__ W_hh, const float* __restrict__ b_ih,
    const float* __restrict__ b_hh, float* __restrict__ out,
    uint32x2* __restrict__ hbuf)
{
  __shared__ __align__(16) unsigned short v_lds[2][BATCH_G * VSTRIDE];

  const int tid  = threadIdx.x;
  const int gid  = blockIdx.x & 63;   // batch group (16 batches)
  const int mid  = blockIdx.x >> 6;   // member 0..3 (computes cols [mid*64,+128) mod 256)
  const int wv   = tid >> 6;          // wave 0..7
  const int l    = tid & 63;
  const int l15  = l & 15, quad = l >> 4;
  const int rg   = wv;                // wave computes cols base + rg*16 + rt*4 + quad

  // ---- A-fragments in SLOT order, 4 row-tiles (16 cols) per wave ----
  bf16x8 afrag[4][10];
#pragma unroll
  for (int rt = 0; rt < 4; ++rt) {
    int gcol = (mid * 64 + rg * 16 + rt * 4 + (l15 >> 2)) & 255;
    int grow = (l15 & 3) * H_DIM + gcol;
    const float* wih_row = W_ih + (long)grow * I_DIM;
    const float* whh_row = W_hh + (long)grow * H_DIM;
#pragma unroll
    for (int s = 0; s < 10; ++s) {
      int kt = slot_kt(s, mid);
      int kbase = kt * 32 + quad * 8;
      ushort8_t a;
#pragma unroll
      for (int e = 0; e < 8; ++e) {
        int k = kbase + e;
        float v = (k < I_DIM) ? wih_row[k] : whh_row[k - I_DIM];
        a[e] = f2bf(v);
      }
      afrag[rt][s] = __builtin_bit_cast(bf16x8, a);
    }
  }

  // ---- bias as acc-init: lane's cell col = (mid*64+rg*16+rt*4+quad)&255 ----
  f32x4 bias[4];
#pragma unroll
  for (int rt = 0; rt < 4; ++rt) {
#pragma unroll
    for (int g = 0; g < 4; ++g) {
      int gcol = (mid * 64 + rg * 16 + rt * 4 + quad) & 255;
      bias[rt][g] = b_ih[g * H_DIM + gcol] + b_hh[g * H_DIM + gcol];
    }
  }

  const int batch = l15;              // 0..15 within group
  float c_reg[4] = {0.f, 0.f, 0.f, 0.f};
  float h_keep[4];

  // ---- x staging: 32 threads per batch row (float2 each) ----
  const int b_stage = tid >> 5;          // 0..15
  const int x_i2    = (tid & 31) * 2;    // 2 floats of x
  const float* xrow = x + ((long)(gid * BATCH_G + b_stage)) * T_STEPS * I_DIM + x_i2;

  // ---- consumer: thread owns ONE dwordx4 = 2 (pair,batch) slots of the 64
  //      remote pairs (partners (mid+2)&3 and (mid+3)&3 canonical slices) ----
  const int p_r = tid >> 3;              // 0..63
  const int bb  = (tid & 7) * 2;         // 0,2,..,14
  const int pabs = (p_r < 32) ? (((mid + 2) & 3) * 32 + p_r)
                              : (((mid + 3) & 3) * 32 + (p_r - 32));
  const uint32x2* ld_base = hbuf + ((long)gid * PAIRS + pabs) * BATCH_G + bb;

  // ---- producer (canonical cols only: waves rg<4): pair = mid*32 + rg*8 +
  //      rt*2 + (quad>>1); lanes l15 contiguous => 128 B runs ----
  uint32x2* st_base = hbuf + ((long)gid * PAIRS + mid * 32 + rg * 8 + (quad >> 1)) * BATCH_G + batch;
  const long buf_stride = (long)NGROUP * PAIRS * BATCH_G;
  const bool producer = (rg < 4);

  // ---- pre-zero full h region of buffer 1 (t=1 phase-1 reads zeros) ----
  {
    int zr = tid >> 5, zc = (tid & 31) * 8;
    uint32x4 z = {0u, 0u, 0u, 0u};
    *(uint32x4*)&v_lds[1][zr * VSTRIDE + I_DIM + zc] = z;
  }

  // ---- x prefetch one step ahead ----
  float2 xv = *(const float2*)xrow;     // row for t=1

  for (int t = 1; t <= T_STEPS; ++t) {
    unsigned short* vbuf = v_lds[t & 1];

    // ---- stage prefetched x_t, then issue the next row's load ----
    {
      ushort2 xb;
      xb.x = f2bf(xv.x); xb.y = f2bf(xv.y);
      *(ushort2*)&vbuf[b_stage * VSTRIDE + x_i2] = xb;
    }
    if (t < T_STEPS) xv = *(const float2*)(xrow + (long)t * I_DIM);

    __syncthreads();   // barrier1: x_t + local h (prev epilogue) visible

    // ---- phase-1a: x tiles (slots 0,1) ----
    f32x4 acc[4] = {bias[0], bias[1], bias[2], bias[3]};
    const unsigned short* vb = vbuf + (unsigned)batch * VSTRIDE + quad * 8;
#pragma unroll
    for (int s = 0; s < 2; ++s) {
      bf16x8 bv = __builtin_bit_cast(bf16x8, *(const uint32x4*)(vb + s * 32));
#pragma unroll
      for (int rt = 0; rt < 4; ++rt)
        acc[rt] = __builtin_amdgcn_mfma_f32_16x16x32_bf16(afrag[rt][s], bv, acc[rt], 0, 0, 0);
    }

    // ---- issue remote poll load (one dwordx4 = 2 tagged slots) ----
    uint32x4 pl;
    const uint32x2* hsrc = ld_base + ((t - 1) & 1) * buf_stride;
    asm volatile("global_load_dwordx4 %0, %1, off sc0 sc1"
                 : "=v"(pl) : "v"(hsrc) : "memory");

    // ---- phase-1b: 4 LOCAL h-tiles (slots 2..5) — 16 MFMA of RT cover ----
#pragma unroll
    for (int s = 2; s < 6; ++s) {
      int off = I_DIM + ((2 * mid + (s - 2)) & 7) * 32;
      bf16x8 bv = __builtin_bit_cast(bf16x8, *(const uint32x4*)(vb + off));
#pragma unroll
      for (int rt = 0; rt < 4; ++rt)
        acc[rt] = __builtin_amdgcn_mfma_f32_16x16x32_bf16(afrag[rt][s], bv, acc[rt], 0, 0, 0);
    }

    // ---- check poll (RT hidden behind phase-1b); bounded retry ----
    {
      asm volatile("s_waitcnt vmcnt(0)" : "+v"(pl) :: "memory");
      const unsigned tag = (unsigned)(t - 1);   // t==1: memset tag 0, data 0
      int it = 0;
      while (!((pl[0] == tag) & (pl[2] == tag))) {
        if (++it > VALVE) break;   // bounded: bench always returns a verdict
        __builtin_amdgcn_s_sleep(1);
        asm volatile("global_load_dwordx4 %0, %1, off sc0 sc1\n\t"
                     "s_waitcnt vmcnt(0)"
                     : "=v"(pl) : "v"(hsrc) : "memory");
      }
      // scatter 2 slots into LDS at canonical col positions
      *(unsigned*)&vbuf[(unsigned)bb * VSTRIDE + I_DIM + pabs * 2]       = pl[1];
      *(unsigned*)&vbuf[(unsigned)(bb + 1) * VSTRIDE + I_DIM + pabs * 2] = pl[3];
    }
    __syncthreads();   // barrier2: remote h staged

    // ---- phase-2: 4 REMOTE h-tiles (slots 6..9) ----
#pragma unroll
    for (int s = 6; s < 10; ++s) {
      int off = I_DIM + ((2 * mid + 4 + (s - 6)) & 7) * 32;
      bf16x8 bv = __builtin_bit_cast(bf16x8, *(const uint32x4*)(vb + off));
#pragma unroll
      for (int rt = 0; rt < 4; ++rt)
        acc[rt] = __builtin_amdgcn_mfma_f32_16x16x32_bf16(afrag[rt][s], bv, acc[rt], 0, 0, 0);
    }

    // ---- cell in registers; ALL computed cols to next LDS; canonical cols
    //      (rg<4) also stored to partners. Producer path: priority boost. ----
    __builtin_amdgcn_s_setprio(1);
    unsigned short* next_h = v_lds[(t + 1) & 1] + (unsigned)batch * VSTRIDE + I_DIM;
#pragma unroll
    for (int rt = 0; rt < 4; ++rt) {
      float cc = sigf(acc[rt][1]) * c_reg[rt] + sigf(acc[rt][0]) * tanhfast(acc[rt][2]);
      float h  = sigf(acc[rt][3]) * tanhfast(cc);
      c_reg[rt] = cc; h_keep[rt] = h;
      unsigned short hb16 = f2bf(h);
      int col = (mid * 64 + rg * 16 + rt * 4 + quad) & 255;
      next_h[col] = hb16;                                       // LDS (own WG)
      unsigned hb = (unsigned)hb16;
      unsigned prt = (unsigned)__shfl_xor((int)hb, 16, 64);     // col^1, same batch
      if (producer && !(quad & 1)) {
        uint32x2 pv;
        pv[0] = (unsigned)t;                  // tag
        pv[1] = hb | (prt << 16);             // (col, col+1)
        st_pair(st_base + rt * 2 * BATCH_G + (t & 1) * buf_stride, pv);  // fire-and-forget
      }
    }
    __builtin_amdgcn_s_setprio(0);
  }

  // ---- outputs: canonical lanes only (rg<4); h_T then c_T, fp32 ----
  if (producer) {
#pragma unroll
    for (int rt = 0; rt < 4; ++rt) {
      int gcol = mid * 64 + rg * 16 + rt * 4 + quad;
      long o = (long)(gid * BATCH_G + batch) * H_DIM + gcol;
      out[o]            = h_keep[rt];
      out[OUT_HALF + o] = c_reg[rt];
    }
  }
}

extern "C" void kernel_launch(void* const* d_in, const int* in_sizes, int n_in,
                              void* d_out, int out_size, void* d_ws, size_t ws_size,
                              hipStream_t stream) {
  const float* x    = (const float*)d_in[0];
  const float* W_ih = (const float*)d_in[1];
  const float* W_hh = (const float*)d_in[2];
  const float* b_ih = (const float*)d_in[3];
  const float* b_hh = (const float*)d_in[4];
  float* out = (float*)d_out;

  uint32x2* hbuf = (uint32x2*)d_ws;   // 2 buffers x 64 groups x 128 pairs x 16 batch x 8 B = 2 MB

  // Clear tags+data: tag 0 == (t=1)-1 makes step 1 read zeros with no special case.
  hipMemsetAsync(d_ws, 0, 2u * NGROUP * PAIRS * BATCH_G * 8u, stream);
  lstm_persistent<<<dim3(256), dim3(512), 0, stream>>>(x, W_ih, W_hh, b_ih, b_hh, out, hbuf);
}

// Round 14
// 928.420 us; speedup vs baseline: 1.1478x; 1.0021x over previous
//
#include <hip/hip_runtime.h>
#include <cstdint>

// LSTM: B=1024, T=336, I=64, H=256, gates 4H=1024, K = I+H = 320.
// R16 = R15 with the occupancy declaration FIXED: __launch_bounds__(512,2).
// R15's counters convicted register spill, not the algorithm: VGPR_Count=128
// vs ~230 needed (afrag[4][10]=160 alone) -> ~100 spilled regs -> WRITE
// +107MB (spill stores), FETCH +54MB (reloads), VALUBusy 57%. The second
// launch_bounds arg is waves/EU: a 512-thr WG at 1 WG/CU = 2 waves/EU, so
// (512,2) sets the VGPR cap to 256 and the weights stay in registers.
// Algorithm unchanged (harness-verified): REDUNDANT-COMPUTE fan-in-2 on the
// R9 base (64 groups x 4 members, 16 batches/group). Member m computes
// gate-cols [m*64,+128) mod 256 -> local phase covers 6/10 k-tiles (24 MFMA
// of poll-RT cover), remote tiles 4 from 2 partners (tail-of-2). LDS staging
// for remote h (R13/14: per-lane direct-to-reg is an L3-BW trap); R9's
// proven poll timing; canonical-only stores; bounded valve; sc0+sc1.

#define NGROUP  64
#define BATCH_G 16
#define T_STEPS 336
#define I_DIM   64
#define H_DIM   256
#define VSTRIDE 336   // ushorts per staged row: x(64) + h(256) + 16 pad
#define PAIRS   128   // h-pairs per batch row (256 cols / 2)
#define OUT_HALF 262144  // 1024*256
#define VALVE   (1 << 12)   // bounded poll: bench always returns a verdict

typedef __attribute__((ext_vector_type(8))) __bf16 bf16x8;
typedef __attribute__((ext_vector_type(8))) unsigned short ushort8_t;
typedef __attribute__((ext_vector_type(4))) float f32x4;
typedef __attribute__((ext_vector_type(4))) unsigned uint32x4;
typedef __attribute__((ext_vector_type(2))) unsigned uint32x2;

__device__ inline unsigned short f2bf(float f) {
  unsigned u = __builtin_bit_cast(unsigned, f);
  return (unsigned short)((u + 0x7fffu + ((u >> 16) & 1u)) >> 16);
}
__device__ inline float sigf(float x) { return 1.f / (1.f + __expf(-x)); }
__device__ inline float tanhfast(float x) { return 1.f - 2.f / (1.f + __expf(2.f * x)); }

// slot s (0..9) -> k-tile kt (0..9). 0,1 = x. 2..5 = the 4 LOCAL h-tiles
// (cols [mid*64, +128) mod 256). 6..9 = the 4 REMOTE h-tiles.
__device__ inline int slot_kt(int s, int mid) {
  return (s < 2) ? s
       : (s < 6) ? (2 + ((2 * mid + (s - 2)) & 7))
       : (2 + ((2 * mid + 4 + (s - 6)) & 7));
}

__device__ inline void st_pair(uint32x2* p, uint32x2 v) {
  asm volatile("global_store_dwordx2 %0, %1, off sc0 sc1" :: "v"(p), "v"(v) : "memory");
}

__global__ __launch_bounds__(512, 2) void lstm_persistent(
    const float* __restrict__ x, const float* __restrict__ W_ih,
    const float* __restrict__ W_hh, const float* __restrict__ b_ih,
    const float* __restrict__ b_hh, float* __restrict__ out,
    uint32x2* __restrict__ hbuf)
{
  __shared__ __align__(16) unsigned short v_lds[2][BATCH_G * VSTRIDE];

  const int tid  = threadIdx.x;
  const int gid  = blockIdx.x & 63;   // batch group (16 batches)
  const int mid  = blockIdx.x >> 6;   // member 0..3 (computes cols [mid*64,+128) mod 256)
  const int wv   = tid >> 6;          // wave 0..7
  const int l    = tid & 63;
  const int l15  = l & 15, quad = l >> 4;
  const int rg   = wv;                // wave computes cols base + rg*16 + rt*4 + quad

  // ---- A-fragments in SLOT order, 4 row-tiles (16 cols) per wave ----
  bf16x8 afrag[4][10];
#pragma unroll
  for (int rt = 0; rt < 4; ++rt) {
    int gcol = (mid * 64 + rg * 16 + rt * 4 + (l15 >> 2)) & 255;
    int grow = (l15 & 3) * H_DIM + gcol;
    const float* wih_row = W_ih + (long)grow * I_DIM;
    const float* whh_row = W_hh + (long)grow * H_DIM;
#pragma unroll
    for (int s = 0; s < 10; ++s) {
      int kt = slot_kt(s, mid);
      int kbase = kt * 32 + quad * 8;
      ushort8_t a;
#pragma unroll
      for (int e = 0; e < 8; ++e) {
        int k = kbase + e;
        float v = (k < I_DIM) ? wih_row[k] : whh_row[k - I_DIM];
        a[e] = f2bf(v);
      }
      afrag[rt][s] = __builtin_bit_cast(bf16x8, a);
    }
  }

  // ---- bias as acc-init: lane's cell col = (mid*64+rg*16+rt*4+quad)&255 ----
  f32x4 bias[4];
#pragma unroll
  for (int rt = 0; rt < 4; ++rt) {
#pragma unroll
    for (int g = 0; g < 4; ++g) {
      int gcol = (mid * 64 + rg * 16 + rt * 4 + quad) & 255;
      bias[rt][g] = b_ih[g * H_DIM + gcol] + b_hh[g * H_DIM + gcol];
    }
  }

  const int batch = l15;              // 0..15 within group
  float c_reg[4] = {0.f, 0.f, 0.f, 0.f};
  float h_keep[4];

  // ---- x staging: 32 threads per batch row (float2 each) ----
  const int b_stage = tid >> 5;          // 0..15
  const int x_i2    = (tid & 31) * 2;    // 2 floats of x
  const float* xrow = x + ((long)(gid * BATCH_G + b_stage)) * T_STEPS * I_DIM + x_i2;

  // ---- consumer: thread owns ONE dwordx4 = 2 (pair,batch) slots of the 64
  //      remote pairs (partners (mid+2)&3 and (mid+3)&3 canonical slices) ----
  const int p_r = tid >> 3;              // 0..63
  const int bb  = (tid & 7) * 2;         // 0,2,..,14
  const int pabs = (p_r < 32) ? (((mid + 2) & 3) * 32 + p_r)
                              : (((mid + 3) & 3) * 32 + (p_r - 32));
  const uint32x2* ld_base = hbuf + ((long)gid * PAIRS + pabs) * BATCH_G + bb;

  // ---- producer (canonical cols only: waves rg<4): pair = mid*32 + rg*8 +
  //      rt*2 + (quad>>1); lanes l15 contiguous => 128 B runs ----
  uint32x2* st_base = hbuf + ((long)gid * PAIRS + mid * 32 + rg * 8 + (quad >> 1)) * BATCH_G + batch;
  const long buf_stride = (long)NGROUP * PAIRS * BATCH_G;
  const bool producer = (rg < 4);

  // ---- pre-zero full h region of buffer 1 (t=1 phase-1 reads zeros) ----
  {
    int zr = tid >> 5, zc = (tid & 31) * 8;
    uint32x4 z = {0u, 0u, 0u, 0u};
    *(uint32x4*)&v_lds[1][zr * VSTRIDE + I_DIM + zc] = z;
  }

  // ---- x prefetch one step ahead ----
  float2 xv = *(const float2*)xrow;     // row for t=1

  for (int t = 1; t <= T_STEPS; ++t) {
    unsigned short* vbuf = v_lds[t & 1];

    // ---- stage prefetched x_t, then issue the next row's load ----
    {
      ushort2 xb;
      xb.x = f2bf(xv.x); xb.y = f2bf(xv.y);
      *(ushort2*)&vbuf[b_stage * VSTRIDE + x_i2] = xb;
    }
    if (t < T_STEPS) xv = *(const float2*)(xrow + (long)t * I_DIM);

    __syncthreads();   // barrier1: x_t + local h (prev epilogue) visible

    // ---- phase-1a: x tiles (slots 0,1) ----
    f32x4 acc[4] = {bias[0], bias[1], bias[2], bias[3]};
    const unsigned short* vb = vbuf + (unsigned)batch * VSTRIDE + quad * 8;
#pragma unroll
    for (int s = 0; s < 2; ++s) {
      bf16x8 bv = __builtin_bit_cast(bf16x8, *(const uint32x4*)(vb + s * 32));
#pragma unroll
      for (int rt = 0; rt < 4; ++rt)
        acc[rt] = __builtin_amdgcn_mfma_f32_16x16x32_bf16(afrag[rt][s], bv, acc[rt], 0, 0, 0);
    }

    // ---- issue remote poll load (one dwordx4 = 2 tagged slots) ----
    uint32x4 pl;
    const uint32x2* hsrc = ld_base + ((t - 1) & 1) * buf_stride;
    asm volatile("global_load_dwordx4 %0, %1, off sc0 sc1"
                 : "=v"(pl) : "v"(hsrc) : "memory");

    // ---- phase-1b: 4 LOCAL h-tiles (slots 2..5) — 16 MFMA of RT cover ----
#pragma unroll
    for (int s = 2; s < 6; ++s) {
      int off = I_DIM + ((2 * mid + (s - 2)) & 7) * 32;
      bf16x8 bv = __builtin_bit_cast(bf16x8, *(const uint32x4*)(vb + off));
#pragma unroll
      for (int rt = 0; rt < 4; ++rt)
        acc[rt] = __builtin_amdgcn_mfma_f32_16x16x32_bf16(afrag[rt][s], bv, acc[rt], 0, 0, 0);
    }

    // ---- check poll (RT hidden behind phase-1b); bounded retry ----
    {
      asm volatile("s_waitcnt vmcnt(0)" : "+v"(pl) :: "memory");
      const unsigned tag = (unsigned)(t - 1);   // t==1: memset tag 0, data 0
      int it = 0;
      while (!((pl[0] == tag) & (pl[2] == tag))) {
        if (++it > VALVE) break;   // bounded: bench always returns a verdict
        __builtin_amdgcn_s_sleep(1);
        asm volatile("global_load_dwordx4 %0, %1, off sc0 sc1\n\t"
                     "s_waitcnt vmcnt(0)"
                     : "=v"(pl) : "v"(hsrc) : "memory");
      }
      // scatter 2 slots into LDS at canonical col positions
      *(unsigned*)&vbuf[(unsigned)bb * VSTRIDE + I_DIM + pabs * 2]       = pl[1];
      *(unsigned*)&vbuf[(unsigned)(bb + 1) * VSTRIDE + I_DIM + pabs * 2] = pl[3];
    }
    __syncthreads();   // barrier2: remote h staged

    // ---- phase-2: 4 REMOTE h-tiles (slots 6..9) ----
#pragma unroll
    for (int s = 6; s < 10; ++s) {
      int off = I_DIM + ((2 * mid + 4 + (s - 6)) & 7) * 32;
      bf16x8 bv = __builtin_bit_cast(bf16x8, *(const uint32x4*)(vb + off));
#pragma unroll
      for (int rt = 0; rt < 4; ++rt)
        acc[rt] = __builtin_amdgcn_mfma_f32_16x16x32_bf16(afrag[rt][s], bv, acc[rt], 0, 0, 0);
    }

    // ---- cell in registers; ALL computed cols to next LDS; canonical cols
    //      (rg<4) also stored to partners. Producer path: priority boost. ----
    __builtin_amdgcn_s_setprio(1);
    unsigned short* next_h = v_lds[(t + 1) & 1] + (unsigned)batch * VSTRIDE + I_DIM;
#pragma unroll
    for (int rt = 0; rt < 4; ++rt) {
      float cc = sigf(acc[rt][1]) * c_reg[rt] + sigf(acc[rt][0]) * tanhfast(acc[rt][2]);
      float h  = sigf(acc[rt][3]) * tanhfast(cc);
      c_reg[rt] = cc; h_keep[rt] = h;
      unsigned short hb16 = f2bf(h);
      int col = (mid * 64 + rg * 16 + rt * 4 + quad) & 255;
      next_h[col] = hb16;                                       // LDS (own WG)
      unsigned hb = (unsigned)hb16;
      unsigned prt = (unsigned)__shfl_xor((int)hb, 16, 64);     // col^1, same batch
      if (producer && !(quad & 1)) {
        uint32x2 pv;
        pv[0] = (unsigned)t;                  // tag
        pv[1] = hb | (prt << 16);             // (col, col+1)
        st_pair(st_base + rt * 2 * BATCH_G + (t & 1) * buf_stride, pv);  // fire-and-forget
      }
    }
    __builtin_amdgcn_s_setprio(0);
  }

  // ---- outputs: canonical lanes only (rg<4); h_T then c_T, fp32 ----
  if (producer) {
#pragma unroll
    for (int rt = 0; rt < 4; ++rt) {
      int gcol = mid * 64 + rg * 16 + rt * 4 + quad;
      long o = (long)(gid * BATCH_G + batch) * H_DIM + gcol;
      out[o]            = h_keep[rt];
      out[OUT_HALF + o] = c_reg[rt];
    }
  }
}

extern "C" void kernel_launch(void* const* d_in, const int* in_sizes, int n_in,
                              void* d_out, int out_size, void* d_ws, size_t ws_size,
                              hipStream_t stream) {
  const float* x    = (const float*)d_in[0];
  const float* W_ih = (const float*)d_in[1];
  const float* W_hh = (const float*)d_in[2];
  const float* b_ih = (const float*)d_in[3];
  const float* b_hh = (const float*)d_in[4];
  float* out = (float*)d_out;

  uint32x2* hbuf = (uint32x2*)d_ws;   // 2 buffers x 64 groups x 128 pairs x 16 batch x 8 B = 2 MB

  // Clear tags+data: tag 0 == (t=1)-1 makes step 1 read zeros with no special case.
  hipMemsetAsync(d_ws, 0, 2u * NGROUP * PAIRS * BATCH_G * 8u, stream);
  lstm_persistent<<<dim3(256), dim3(512), 0, stream>>>(x, W_ih, W_hh, b_ih, b_hh, out, hbuf);
}